// Round 5
// baseline (123.135 us; speedup 1.0000x reference)
//
#include <hip/hip_runtime.h>
#include <math.h>

#define IN_F 256
#define OUT_F 128
#define NHEAD 2
#define ALPHA 0.2f
#define NN 4096          // compile-time N (problem-fixed); enables full unroll
#define NCAP 128         // max neighbors/row (binom(4096,.005) max ~45 + diag)

typedef __attribute__((ext_vector_type(8))) short short8;
typedef __attribute__((ext_vector_type(4))) float f32x4;
typedef const __attribute__((address_space(1))) void* gas_ptr;
typedef __attribute__((address_space(3))) void* las_ptr;

__device__ __forceinline__ void async_copy16(const void* g, void* l) {
  __builtin_amdgcn_global_load_lds((gas_ptr)g, (las_ptr)l, 16, 0, 0);
}

__device__ __forceinline__ ushort f2bf(float f) {
  unsigned u = __float_as_uint(f);
  u += 0x7fffu + ((u >> 16) & 1u);  // RNE
  return (ushort)(u >> 16);
}

__device__ __forceinline__ float lrelu(float t) { return t > 0.f ? t : ALPHA * t; }

// ---------------------------------------------------------------------------
// prep_w: Wt[h][o][k] = bf16(W[h][k][o])  (transpose + cast; 64 blocks)
// ---------------------------------------------------------------------------
__global__ __launch_bounds__(256) void prep_w(
    const float* __restrict__ W, ushort* __restrict__ Wt) {
  int p = blockIdx.x * 256 + threadIdx.x;   // 16384 ushort4 outputs
  int h = p >> 13;
  int rem = p & 8191;
  int c = rem >> 7;       // k-quad 0..63
  int o = rem & 127;
  const float* wsrc = W + h * (IN_F * OUT_F) + (4 * c) * OUT_F + o;
  ushort4 ov;
  ov.x = f2bf(wsrc[0 * OUT_F]);
  ov.y = f2bf(wsrc[1 * OUT_F]);
  ov.z = f2bf(wsrc[2 * OUT_F]);
  ov.w = f2bf(wsrc[3 * OUT_F]);
  *(ushort4*)(Wt + ((size_t)h * OUT_F + o) * IN_F + 4 * c) = ov;
}

// ---------------------------------------------------------------------------
// gemm_mfma: xt[h][r][o] = sum_k bf16(x[r][k]) * Wt[h][o][k]; fused e1/e2.
// A staged from fp32 x with in-register bf16 cast; B via global_load_lds(16).
// ---------------------------------------------------------------------------
__global__ __launch_bounds__(256) void gemm_mfma(
    const float* __restrict__ x, const ushort* __restrict__ Wt,
    const float* __restrict__ a,
    float* __restrict__ xt, float* __restrict__ e1, float* __restrict__ e2) {
  __shared__ ushort sA[32 * 64];    //  4 KB
  __shared__ ushort sB[128 * 64];   // 16 KB
  __shared__ float sa[2 * OUT_F];
  __shared__ float se1[32], se2[32];

  const int h = blockIdx.y;
  const int rowBase = blockIdx.x * 32;
  const int tid = threadIdx.x;
  const int wave = tid >> 6, lane = tid & 63;
  const int wr = wave & 1, wc = wave >> 1;
  const int q = lane >> 4, l16 = lane & 15;

  sa[tid] = a[h * (2 * OUT_F) + tid];

  f32x4 acc[4];
#pragma unroll
  for (int i = 0; i < 4; ++i) acc[i] = (f32x4)(0.0f);

  const float* xbase = x + (size_t)rowBase * IN_F;
  const char* wbase = (const char*)(Wt + (size_t)h * (OUT_F * IN_F));
  const int ar = tid >> 3;          // 0..31
  const int ak = (tid & 7) * 8;     // 0..56

  for (int k0 = 0; k0 < IN_F; k0 += 64) {
    // B tile: 128x64 bf16 = 1024 granules of 16B, 4/thread (async)
#pragma unroll
    for (int it = 0; it < 4; ++it) {
      int g = it * 256 + tid;
      int r = g >> 3, c8 = g & 7;
      async_copy16(wbase + r * 512 + k0 * 2 + c8 * 16,
                   (char*)sB + (size_t)(it * 256 + wave * 64) * 16);
    }
    // A tile: 32x64 fp32 -> bf16 in-register -> LDS (8 floats/thread)
    {
      const float* src = xbase + (size_t)ar * IN_F + k0 + ak;
      float4 va = *(const float4*)src;
      float4 vb = *(const float4*)(src + 4);
      union { short8 s8; ushort u[8]; } pk;
      pk.u[0] = f2bf(va.x); pk.u[1] = f2bf(va.y);
      pk.u[2] = f2bf(va.z); pk.u[3] = f2bf(va.w);
      pk.u[4] = f2bf(vb.x); pk.u[5] = f2bf(vb.y);
      pk.u[6] = f2bf(vb.z); pk.u[7] = f2bf(vb.w);
      *(short8*)(sA + ar * 64 + ak) = pk.s8;
    }
    __syncthreads();

#pragma unroll
    for (int ks = 0; ks < 64; ks += 32) {
      short8 af = *(const short8*)(sA + (wr * 16 + l16) * 64 + ks + q * 8);
#pragma unroll
      for (int ct = 0; ct < 4; ++ct) {
        int col = wc * 64 + ct * 16 + l16;
        short8 bf = *(const short8*)(sB + col * 64 + ks + q * 8);
        acc[ct] = __builtin_amdgcn_mfma_f32_16x16x32_bf16(af, bf, acc[ct], 0, 0, 0);
      }
    }
    __syncthreads();
  }

  // epilogue 1: store xt (D: row = q*4+reg, col = l16)
#pragma unroll
  for (int ct = 0; ct < 4; ++ct) {
    int col = wc * 64 + ct * 16 + l16;
#pragma unroll
    for (int reg = 0; reg < 4; ++reg) {
      int row = rowBase + wr * 16 + q * 4 + reg;
      xt[((size_t)h * NN + row) * OUT_F + col] = acc[ct][reg];
    }
  }

  // epilogue 2: fused e1/e2
  float pe1[4], pe2[4];
#pragma unroll
  for (int reg = 0; reg < 4; ++reg) { pe1[reg] = 0.f; pe2[reg] = 0.f; }
#pragma unroll
  for (int ct = 0; ct < 4; ++ct) {
    int col = wc * 64 + ct * 16 + l16;
    float a1v = sa[col], a2v = sa[OUT_F + col];
#pragma unroll
    for (int reg = 0; reg < 4; ++reg) {
      pe1[reg] = fmaf(acc[ct][reg], a1v, pe1[reg]);
      pe2[reg] = fmaf(acc[ct][reg], a2v, pe2[reg]);
    }
  }
#pragma unroll
  for (int off = 1; off < 16; off <<= 1) {
#pragma unroll
    for (int reg = 0; reg < 4; ++reg) {
      pe1[reg] += __shfl_xor(pe1[reg], off, 64);
      pe2[reg] += __shfl_xor(pe2[reg], off, 64);
    }
  }
  if (wc == 0 && l16 == 0) {
#pragma unroll
    for (int reg = 0; reg < 4; ++reg) {
      int r = wr * 16 + q * 4 + reg;
      se1[r] = pe1[reg];
      se2[r] = pe2[reg];
    }
  }
  __syncthreads();
  if (wc == 1 && l16 == 0) {
#pragma unroll
    for (int reg = 0; reg < 4; ++reg) {
      int r = wr * 16 + q * 4 + reg;
      se1[r] += pe1[reg];
      se2[r] += pe2[reg];
    }
  }
  __syncthreads();
  if (tid < 32) {
    e1[(size_t)h * NN + rowBase + tid] = se1[tid];
    e2[(size_t)h * NN + rowBase + tid] = se2[tid];
  }
}

// ---------------------------------------------------------------------------
// gat_aggregate: 2 rows per block (32 KB contiguous scan, fully unrolled,
// 8 outstanding float4/thread). Scores written at compaction; parallel
// shfl max/sum (m <= NCAP <= 256 -> one element per thread); gather x4.
// ---------------------------------------------------------------------------
__global__ __launch_bounds__(256) void gat_aggregate(
    const float* __restrict__ adj, const float* __restrict__ xt,
    const float* __restrict__ e1, const float* __restrict__ e2,
    float* __restrict__ out) {
  __shared__ int s_nbr[2][NCAP];
  __shared__ float s_sc[2][2][NCAP];   // [row][head][k]
  __shared__ int s_cnt[2];
  __shared__ float s_mx[4][4];         // [wave][list]
  __shared__ float s_sm[4][4];

  const int i0 = blockIdx.x * 2;
  const int tid = threadIdx.x;
  const int wave = tid >> 6, lane = tid & 63;
  if (tid < 2) s_cnt[tid] = 0;
  __syncthreads();

  // e1 per (row,head)
  const float e1v[2][2] = {{e1[i0], e1[NN + i0]}, {e1[i0 + 1], e1[NN + i0 + 1]}};

  // ---- phase 1: batched scan of 2 contiguous rows (8192 floats) ----
  const float4* base4 = (const float4*)(adj + (size_t)i0 * NN);
  float4 v[8];
#pragma unroll
  for (int it = 0; it < 8; ++it) v[it] = base4[tid + it * 256];

#pragma unroll
  for (int it = 0; it < 8; ++it) {
    int c = tid + it * 256;
    float vals[4] = {v[it].x, v[it].y, v[it].z, v[it].w};
#pragma unroll
    for (int s = 0; s < 4; ++s) {
      int e = c * 4 + s;
      int r = e >> 12;           // 0 or 1
      int col = e & (NN - 1);
      if (vals[s] > 0.f || col == i0 + r) {
        int p = atomicAdd(&s_cnt[r], 1);
        if (p < NCAP) {
          s_nbr[r][p] = col;
          s_sc[r][0][p] = lrelu(e1v[r][0] + e2[col]);
          s_sc[r][1][p] = lrelu(e1v[r][1] + e2[NN + col]);
        }
      }
    }
  }
  __syncthreads();
  const int m0 = s_cnt[0] < NCAP ? s_cnt[0] : NCAP;
  const int m1 = s_cnt[1] < NCAP ? s_cnt[1] : NCAP;

  // ---- phase 2: parallel max per list (lists: 0=(r0,h0) 1=(r0,h1) 2=(r1,h0) 3=(r1,h1))
  float t0 = (tid < m0) ? s_sc[0][0][tid] : -3.0e38f;
  float t1 = (tid < m0) ? s_sc[0][1][tid] : -3.0e38f;
  float t2 = (tid < m1) ? s_sc[1][0][tid] : -3.0e38f;
  float t3 = (tid < m1) ? s_sc[1][1][tid] : -3.0e38f;
#pragma unroll
  for (int off = 32; off > 0; off >>= 1) {
    t0 = fmaxf(t0, __shfl_xor(t0, off, 64));
    t1 = fmaxf(t1, __shfl_xor(t1, off, 64));
    t2 = fmaxf(t2, __shfl_xor(t2, off, 64));
    t3 = fmaxf(t3, __shfl_xor(t3, off, 64));
  }
  if (lane == 0) {
    s_mx[wave][0] = t0; s_mx[wave][1] = t1;
    s_mx[wave][2] = t2; s_mx[wave][3] = t3;
  }
  __syncthreads();
  float mx[4];
#pragma unroll
  for (int l = 0; l < 4; ++l)
    mx[l] = fmaxf(fmaxf(s_mx[0][l], s_mx[1][l]), fmaxf(s_mx[2][l], s_mx[3][l]));

  // ---- phase 3: exp (write back) + parallel sum ----
  float g0 = 0.f, g1 = 0.f, g2 = 0.f, g3 = 0.f;
  if (tid < m0) {
    g0 = __expf(s_sc[0][0][tid] - mx[0]); s_sc[0][0][tid] = g0;
    g1 = __expf(s_sc[0][1][tid] - mx[1]); s_sc[0][1][tid] = g1;
  }
  if (tid < m1) {
    g2 = __expf(s_sc[1][0][tid] - mx[2]); s_sc[1][0][tid] = g2;
    g3 = __expf(s_sc[1][1][tid] - mx[3]); s_sc[1][1][tid] = g3;
  }
#pragma unroll
  for (int off = 32; off > 0; off >>= 1) {
    g0 += __shfl_xor(g0, off, 64);
    g1 += __shfl_xor(g1, off, 64);
    g2 += __shfl_xor(g2, off, 64);
    g3 += __shfl_xor(g3, off, 64);
  }
  if (lane == 0) {
    s_sm[wave][0] = g0; s_sm[wave][1] = g1;
    s_sm[wave][2] = g2; s_sm[wave][3] = g3;
  }
  __syncthreads();
  float linv[4];
#pragma unroll
  for (int l = 0; l < 4; ++l)
    linv[l] = 1.0f / (((s_sm[0][l] + s_sm[1][l]) + (s_sm[2][l] + s_sm[3][l])));

  // ---- phase 4: gather-accumulate, both rows, x4 unrolled ----
  const int h = tid >> 7;
  const int o = tid & 127;
  const float* xth = xt + (size_t)h * NN * OUT_F + o;
  const float* pp0 = s_sc[0][h];
  const float* pp1 = s_sc[1][h];

  float acc0 = 0.f, acc1 = 0.f;
  int k = 0;
  for (; k + 4 <= m0; k += 4) {
    int j0 = s_nbr[0][k], j1 = s_nbr[0][k + 1], j2 = s_nbr[0][k + 2], j3 = s_nbr[0][k + 3];
    float q0 = pp0[k], q1 = pp0[k + 1], q2 = pp0[k + 2], q3 = pp0[k + 3];
    float w0 = xth[(size_t)j0 * OUT_F], w1 = xth[(size_t)j1 * OUT_F];
    float w2 = xth[(size_t)j2 * OUT_F], w3 = xth[(size_t)j3 * OUT_F];
    acc0 = fmaf(q0, w0, acc0); acc0 = fmaf(q1, w1, acc0);
    acc0 = fmaf(q2, w2, acc0); acc0 = fmaf(q3, w3, acc0);
  }
  for (; k < m0; ++k) acc0 = fmaf(pp0[k], xth[(size_t)s_nbr[0][k] * OUT_F], acc0);
  k = 0;
  for (; k + 4 <= m1; k += 4) {
    int j0 = s_nbr[1][k], j1 = s_nbr[1][k + 1], j2 = s_nbr[1][k + 2], j3 = s_nbr[1][k + 3];
    float q0 = pp1[k], q1 = pp1[k + 1], q2 = pp1[k + 2], q3 = pp1[k + 3];
    float w0 = xth[(size_t)j0 * OUT_F], w1 = xth[(size_t)j1 * OUT_F];
    float w2 = xth[(size_t)j2 * OUT_F], w3 = xth[(size_t)j3 * OUT_F];
    acc1 = fmaf(q0, w0, acc1); acc1 = fmaf(q1, w1, acc1);
    acc1 = fmaf(q2, w2, acc1); acc1 = fmaf(q3, w3, acc1);
  }
  for (; k < m1; ++k) acc1 = fmaf(pp1[k], xth[(size_t)s_nbr[1][k] * OUT_F], acc1);

  acc0 *= linv[h];
  acc1 *= linv[2 + h];
  float r0 = acc0 > 0.f ? acc0 : (__expf(acc0) - 1.0f);
  float r1 = acc1 > 0.f ? acc1 : (__expf(acc1) - 1.0f);
  out[((size_t)h * NN + i0) * OUT_F + o] = r0;
  out[((size_t)h * NN + i0 + 1) * OUT_F + o] = r1;
}

// ---------------------------------------------------------------------------
extern "C" void kernel_launch(void* const* d_in, const int* in_sizes, int n_in,
                              void* d_out, int out_size, void* d_ws, size_t ws_size,
                              hipStream_t stream) {
  const float* x   = (const float*)d_in[0];
  const float* adj = (const float*)d_in[1];
  const float* W   = (const float*)d_in[2];
  const float* a   = (const float*)d_in[3];
  float* out = (float*)d_out;

  float* xt = (float*)d_ws;                                  // H*N*OUT_F f32 (4 MB)
  float* e1 = xt + (size_t)NHEAD * NN * OUT_F;               // H*N
  float* e2 = e1 + (size_t)NHEAD * NN;                       // H*N
  ushort* Wt = (ushort*)(e2 + (size_t)NHEAD * NN);           // H*OUT_F*IN_F bf16

  prep_w<<<64, 256, 0, stream>>>(W, Wt);
  gemm_mfma<<<dim3(NN / 32, NHEAD), 256, 0, stream>>>(x, Wt, a, xt, e1, e2);
  gat_aggregate<<<NN / 2, 256, 0, stream>>>(adj, xt, e1, e2, out);
}

// Round 6
// 116.564 us; speedup vs baseline: 1.0564x; 1.0564x over previous
//
#include <hip/hip_runtime.h>
#include <math.h>

#define IN_F 256
#define OUT_F 128
#define NHEAD 2
#define ALPHA 0.2f
#define NN 4096          // compile-time N (problem-fixed)
#define NCAP 256         // max neighbors/row (max degree ~45 + diag)

typedef __attribute__((ext_vector_type(8))) short short8;
typedef __attribute__((ext_vector_type(4))) float f32x4;
typedef const __attribute__((address_space(1))) void* gas_ptr;
typedef __attribute__((address_space(3))) void* las_ptr;

__device__ __forceinline__ void async_copy16(const void* g, void* l) {
  __builtin_amdgcn_global_load_lds((gas_ptr)g, (las_ptr)l, 16, 0, 0);
}

__device__ __forceinline__ ushort f2bf(float f) {
  unsigned u = __float_as_uint(f);
  u += 0x7fffu + ((u >> 16) & 1u);  // RNE
  return (ushort)(u >> 16);
}

__device__ __forceinline__ float lrelu(float t) { return t > 0.f ? t : ALPHA * t; }

// ---------------------------------------------------------------------------
// prep_cast: blocks [0,1024): xb = bf16(x); blocks [1024,1088): Wt[h][o][k]
// ---------------------------------------------------------------------------
__global__ __launch_bounds__(256) void prep_cast(
    const float* __restrict__ x, const float* __restrict__ W,
    ushort* __restrict__ xb, ushort* __restrict__ Wt) {
  const int b = blockIdx.x;
  const int tid = threadIdx.x;
  if (b < 1024) {
    int i0 = b * 1024 + tid * 4;
    float4 v = *(const float4*)(x + i0);
    ushort4 o;
    o.x = f2bf(v.x); o.y = f2bf(v.y); o.z = f2bf(v.z); o.w = f2bf(v.w);
    *(ushort4*)(xb + i0) = o;
  } else {
    int p = (b - 1024) * 256 + tid;
    int h = p >> 13;
    int rem = p & 8191;
    int c = rem >> 7;       // k-quad 0..63
    int o = rem & 127;
    const float* wsrc = W + h * (IN_F * OUT_F) + (4 * c) * OUT_F + o;
    ushort4 ov;
    ov.x = f2bf(wsrc[0 * OUT_F]);
    ov.y = f2bf(wsrc[1 * OUT_F]);
    ov.z = f2bf(wsrc[2 * OUT_F]);
    ov.w = f2bf(wsrc[3 * OUT_F]);
    *(ushort4*)(Wt + ((size_t)h * OUT_F + o) * IN_F + 4 * c) = ov;
  }
}

// ---------------------------------------------------------------------------
// gemm_mfma (R4-proven): xt = xb @ Wt^T per head, bf16 MFMA, fused e1/e2.
// Both tiles staged via global_load_lds width=16.
// ---------------------------------------------------------------------------
__global__ __launch_bounds__(256) void gemm_mfma(
    const ushort* __restrict__ xb, const ushort* __restrict__ Wt,
    const float* __restrict__ a,
    float* __restrict__ xt, float* __restrict__ e1, float* __restrict__ e2) {
  __shared__ ushort sA[32 * 64];    //  4 KB
  __shared__ ushort sB[128 * 64];   // 16 KB
  __shared__ float sa[2 * OUT_F];
  __shared__ float se1[32], se2[32];

  const int h = blockIdx.y;
  const int rowBase = blockIdx.x * 32;
  const int tid = threadIdx.x;
  const int wave = tid >> 6, lane = tid & 63;
  const int wr = wave & 1, wc = wave >> 1;
  const int q = lane >> 4, l16 = lane & 15;

  sa[tid] = a[h * (2 * OUT_F) + tid];

  f32x4 acc[4];
#pragma unroll
  for (int i = 0; i < 4; ++i) acc[i] = (f32x4)(0.0f);

  const char* xbase = (const char*)(xb + (size_t)rowBase * IN_F);
  const char* wbase = (const char*)(Wt + (size_t)h * (OUT_F * IN_F));

  for (int k0 = 0; k0 < IN_F; k0 += 64) {
    // A tile: 32x64 bf16 = 256 granules of 16 B; granule g = tid.
    {
      int r = tid >> 3, c8 = tid & 7;
      async_copy16(xbase + r * 512 + k0 * 2 + c8 * 16,
                   (char*)sA + (size_t)wave * 1024);
    }
    // B tile: 128x64 bf16 = 1024 granules, 4 per thread.
#pragma unroll
    for (int it = 0; it < 4; ++it) {
      int g = it * 256 + tid;
      int r = g >> 3, c8 = g & 7;
      async_copy16(wbase + r * 512 + k0 * 2 + c8 * 16,
                   (char*)sB + (size_t)(it * 256 + wave * 64) * 16);
    }
    __syncthreads();

#pragma unroll
    for (int ks = 0; ks < 64; ks += 32) {
      short8 af = *(const short8*)(sA + (wr * 16 + l16) * 64 + ks + q * 8);
#pragma unroll
      for (int ct = 0; ct < 4; ++ct) {
        int col = wc * 64 + ct * 16 + l16;
        short8 bf = *(const short8*)(sB + col * 64 + ks + q * 8);
        acc[ct] = __builtin_amdgcn_mfma_f32_16x16x32_bf16(af, bf, acc[ct], 0, 0, 0);
      }
    }
    __syncthreads();
  }

  // epilogue 1: store xt (D: row = q*4+reg, col = l16)
#pragma unroll
  for (int ct = 0; ct < 4; ++ct) {
    int col = wc * 64 + ct * 16 + l16;
#pragma unroll
    for (int reg = 0; reg < 4; ++reg) {
      int row = rowBase + wr * 16 + q * 4 + reg;
      xt[((size_t)h * NN + row) * OUT_F + col] = acc[ct][reg];
    }
  }

  // epilogue 2: fused e1/e2
  float pe1[4], pe2[4];
#pragma unroll
  for (int reg = 0; reg < 4; ++reg) { pe1[reg] = 0.f; pe2[reg] = 0.f; }
#pragma unroll
  for (int ct = 0; ct < 4; ++ct) {
    int col = wc * 64 + ct * 16 + l16;
    float a1v = sa[col], a2v = sa[OUT_F + col];
#pragma unroll
    for (int reg = 0; reg < 4; ++reg) {
      pe1[reg] = fmaf(acc[ct][reg], a1v, pe1[reg]);
      pe2[reg] = fmaf(acc[ct][reg], a2v, pe2[reg]);
    }
  }
#pragma unroll
  for (int off = 1; off < 16; off <<= 1) {
#pragma unroll
    for (int reg = 0; reg < 4; ++reg) {
      pe1[reg] += __shfl_xor(pe1[reg], off, 64);
      pe2[reg] += __shfl_xor(pe2[reg], off, 64);
    }
  }
  if (wc == 0 && l16 == 0) {
#pragma unroll
    for (int reg = 0; reg < 4; ++reg) {
      int r = wr * 16 + q * 4 + reg;
      se1[r] = pe1[reg];
      se2[r] = pe2[reg];
    }
  }
  __syncthreads();
  if (wc == 1 && l16 == 0) {
#pragma unroll
    for (int reg = 0; reg < 4; ++reg) {
      int r = wr * 16 + q * 4 + reg;
      se1[r] += pe1[reg];
      se2[r] += pe2[reg];
    }
  }
  __syncthreads();
  if (tid < 32) {
    e1[(size_t)h * NN + rowBase + tid] = se1[tid];
    e2[(size_t)h * NN + rowBase + tid] = se2[tid];
  }
}

// ---------------------------------------------------------------------------
// gat_aggregate: 1 row/block (4096 blocks). Scan: 4 float4 loads hoisted
// (compile-time bounds, all in flight). Scores in a dedicated non-divergent
// phase. Parallel shfl max/sum. Gather x4 unrolled. Output [h][i][o].
// ---------------------------------------------------------------------------
__global__ __launch_bounds__(256) void gat_aggregate(
    const float* __restrict__ adj, const float* __restrict__ xt,
    const float* __restrict__ e1, const float* __restrict__ e2,
    float* __restrict__ out) {
  __shared__ int s_nbr[NCAP];
  __shared__ float s_sc0[NCAP];
  __shared__ float s_sc1[NCAP];
  __shared__ int s_cnt;
  __shared__ float s_red[4][2];

  const int i = blockIdx.x;
  const int tid = threadIdx.x;
  const int wave = tid >> 6, lane = tid & 63;
  if (tid == 0) s_cnt = 0;
  __syncthreads();

  // ---- phase 1: scan (all 4 wave-wide loads in flight before processing) ----
  const float4* arow4 = (const float4*)(adj + (size_t)i * NN);
  float4 v[4];
#pragma unroll
  for (int it = 0; it < 4; ++it) v[it] = arow4[tid + it * 256];

#pragma unroll
  for (int it = 0; it < 4; ++it) {
    int j = (tid + it * 256) * 4;
    float vals[4] = {v[it].x, v[it].y, v[it].z, v[it].w};
#pragma unroll
    for (int s = 0; s < 4; ++s) {
      if (vals[s] > 0.f || j + s == i) {
        int p = atomicAdd(&s_cnt, 1);
        if (p < NCAP) s_nbr[p] = j + s;
      }
    }
  }
  __syncthreads();
  const int m = s_cnt < NCAP ? s_cnt : NCAP;

  // ---- phase 2: scores (non-divergent, one gather per thread) ----
  const float e10 = e1[i];
  const float e11 = e1[NN + i];
  if (tid < m) {
    int j = s_nbr[tid];
    s_sc0[tid] = lrelu(e10 + e2[j]);
    s_sc1[tid] = lrelu(e11 + e2[NN + j]);
  }
  __syncthreads();

  // ---- phase 3: parallel max (both heads) ----
  float t0 = (tid < m) ? s_sc0[tid] : -3.0e38f;
  float t1 = (tid < m) ? s_sc1[tid] : -3.0e38f;
#pragma unroll
  for (int off = 32; off > 0; off >>= 1) {
    t0 = fmaxf(t0, __shfl_xor(t0, off, 64));
    t1 = fmaxf(t1, __shfl_xor(t1, off, 64));
  }
  if (lane == 0) { s_red[wave][0] = t0; s_red[wave][1] = t1; }
  __syncthreads();
  const float mx0 = fmaxf(fmaxf(s_red[0][0], s_red[1][0]), fmaxf(s_red[2][0], s_red[3][0]));
  const float mx1 = fmaxf(fmaxf(s_red[0][1], s_red[1][1]), fmaxf(s_red[2][1], s_red[3][1]));
  __syncthreads();

  // ---- phase 4: exp + parallel sum ----
  float g0 = 0.f, g1 = 0.f;
  if (tid < m) {
    g0 = __expf(s_sc0[tid] - mx0); s_sc0[tid] = g0;
    g1 = __expf(s_sc1[tid] - mx1); s_sc1[tid] = g1;
  }
#pragma unroll
  for (int off = 32; off > 0; off >>= 1) {
    g0 += __shfl_xor(g0, off, 64);
    g1 += __shfl_xor(g1, off, 64);
  }
  if (lane == 0) { s_red[wave][0] = g0; s_red[wave][1] = g1; }
  __syncthreads();
  const float l0 = (s_red[0][0] + s_red[1][0]) + (s_red[2][0] + s_red[3][0]);
  const float l1 = (s_red[0][1] + s_red[1][1]) + (s_red[2][1] + s_red[3][1]);

  // ---- phase 5: gather-accumulate (x4 unrolled), post-normalize, ELU ----
  const int h = tid >> 7;
  const int o = tid & 127;
  const float* pp = h ? s_sc1 : s_sc0;
  const float linv = 1.0f / (h ? l1 : l0);
  const float* xth = xt + (size_t)h * NN * OUT_F + o;

  float acc = 0.f;
  int k = 0;
  for (; k + 4 <= m; k += 4) {
    int j0 = s_nbr[k], j1 = s_nbr[k + 1], j2 = s_nbr[k + 2], j3 = s_nbr[k + 3];
    float q0 = pp[k], q1 = pp[k + 1], q2 = pp[k + 2], q3 = pp[k + 3];
    float w0 = xth[(size_t)j0 * OUT_F], w1 = xth[(size_t)j1 * OUT_F];
    float w2 = xth[(size_t)j2 * OUT_F], w3 = xth[(size_t)j3 * OUT_F];
    acc = fmaf(q0, w0, acc); acc = fmaf(q1, w1, acc);
    acc = fmaf(q2, w2, acc); acc = fmaf(q3, w3, acc);
  }
  for (; k < m; ++k) acc = fmaf(pp[k], xth[(size_t)s_nbr[k] * OUT_F], acc);

  acc *= linv;
  float r = acc > 0.f ? acc : (__expf(acc) - 1.0f);
  out[((size_t)h * NN + i) * OUT_F + o] = r;
}

// ---------------------------------------------------------------------------
extern "C" void kernel_launch(void* const* d_in, const int* in_sizes, int n_in,
                              void* d_out, int out_size, void* d_ws, size_t ws_size,
                              hipStream_t stream) {
  const float* x   = (const float*)d_in[0];
  const float* adj = (const float*)d_in[1];
  const float* W   = (const float*)d_in[2];
  const float* a   = (const float*)d_in[3];
  float* out = (float*)d_out;

  float* xt = (float*)d_ws;                                  // H*N*OUT_F f32 (4 MB)
  float* e1 = xt + (size_t)NHEAD * NN * OUT_F;               // H*N
  float* e2 = e1 + (size_t)NHEAD * NN;                       // H*N
  ushort* xb = (ushort*)(e2 + (size_t)NHEAD * NN);           // N*IN_F bf16 (2 MB)
  ushort* Wt = xb + (size_t)NN * IN_F;                       // H*OUT_F*IN_F bf16

  prep_cast<<<1088, 256, 0, stream>>>(x, W, xb, Wt);
  gemm_mfma<<<dim3(NN / 32, NHEAD), 256, 0, stream>>>(xb, Wt, a, xt, e1, e2);
  gat_aggregate<<<NN, 256, 0, stream>>>(adj, xt, e1, e2, out);
}

// Round 7
// 115.396 us; speedup vs baseline: 1.0671x; 1.0101x over previous
//
#include <hip/hip_runtime.h>
#include <math.h>

#define IN_F 256
#define OUT_F 128
#define NHEAD 2
#define ALPHA 0.2f
#define NN 4096          // compile-time N (problem-fixed)
#define NCAP 256         // max neighbors/row (max degree ~45 + diag)

typedef __attribute__((ext_vector_type(8))) short short8;
typedef __attribute__((ext_vector_type(4))) float f32x4;
typedef const __attribute__((address_space(1))) void* gas_ptr;
typedef __attribute__((address_space(3))) void* las_ptr;

__device__ __forceinline__ void async_copy16(const void* g, void* l) {
  __builtin_amdgcn_global_load_lds((gas_ptr)g, (las_ptr)l, 16, 0, 0);
}

__device__ __forceinline__ ushort f2bf(float f) {
  unsigned u = __float_as_uint(f);
  u += 0x7fffu + ((u >> 16) & 1u);  // RNE
  return (ushort)(u >> 16);
}

__device__ __forceinline__ float lrelu(float t) { return t > 0.f ? t : ALPHA * t; }

// ---------------------------------------------------------------------------
// prep_w: Wt[h][o][k] = bf16(W[h][k][o])  (transpose + cast; 64 blocks)
// ---------------------------------------------------------------------------
__global__ __launch_bounds__(256) void prep_w(
    const float* __restrict__ W, ushort* __restrict__ Wt) {
  int p = blockIdx.x * 256 + threadIdx.x;   // 16384 ushort4 outputs
  int h = p >> 13;
  int rem = p & 8191;
  int c = rem >> 7;       // k-quad 0..63
  int o = rem & 127;
  const float* wsrc = W + h * (IN_F * OUT_F) + (4 * c) * OUT_F + o;
  ushort4 ov;
  ov.x = f2bf(wsrc[0 * OUT_F]);
  ov.y = f2bf(wsrc[1 * OUT_F]);
  ov.z = f2bf(wsrc[2 * OUT_F]);
  ov.w = f2bf(wsrc[3 * OUT_F]);
  *(ushort4*)(Wt + ((size_t)h * OUT_F + o) * IN_F + 4 * c) = ov;
}

// ---------------------------------------------------------------------------
// gemm_mfma: xt[h][r][o] = sum_k bf16(x[r][k]) * Wt[h][o][k]; fused e1/e2.
// A: ALL 4 K-chunks prefetched to registers at entry (8 independent
// dwordx4 loads in flight), cast to bf16 per chunk -> LDS. No sync-load
// stall inside the K-loop (R5 failure mode avoided). B: async width-16.
// ---------------------------------------------------------------------------
__global__ __launch_bounds__(256) void gemm_mfma(
    const float* __restrict__ x, const ushort* __restrict__ Wt,
    const float* __restrict__ a,
    float* __restrict__ xt, float* __restrict__ e1, float* __restrict__ e2) {
  __shared__ ushort sA[32 * 64];    //  4 KB
  __shared__ ushort sB[128 * 64];   // 16 KB
  __shared__ float sa[2 * OUT_F];
  __shared__ float se1[32], se2[32];

  const int h = blockIdx.y;
  const int rowBase = blockIdx.x * 32;
  const int tid = threadIdx.x;
  const int wave = tid >> 6, lane = tid & 63;
  const int wr = wave & 1, wc = wave >> 1;
  const int q = lane >> 4, l16 = lane & 15;
  const int ar = tid >> 3;          // A row 0..31
  const int ak = (tid & 7) * 8;     // A col-octet 0..56

  // A prefetch: full row-slice for all 4 chunks (8 float4s, independent)
  const float* xrow = x + (size_t)(rowBase + ar) * IN_F + ak;
  float4 ax[8];
#pragma unroll
  for (int c = 0; c < 4; ++c) {
    ax[2 * c]     = *(const float4*)(xrow + 64 * c);
    ax[2 * c + 1] = *(const float4*)(xrow + 64 * c + 4);
  }

  sa[tid] = a[h * (2 * OUT_F) + tid];

  f32x4 acc[4];
#pragma unroll
  for (int i = 0; i < 4; ++i) acc[i] = (f32x4)(0.0f);

  const char* wbase = (const char*)(Wt + (size_t)h * (OUT_F * IN_F));

#pragma unroll
  for (int c = 0; c < 4; ++c) {
    const int k0 = c * 64;
    // B tile: 128x64 bf16 = 1024 granules of 16B, 4/thread (async)
#pragma unroll
    for (int it = 0; it < 4; ++it) {
      int g = it * 256 + tid;
      int r = g >> 3, c8 = g & 7;
      async_copy16(wbase + r * 512 + k0 * 2 + c8 * 16,
                   (char*)sB + (size_t)(it * 256 + wave * 64) * 16);
    }
    // A tile: cast prefetched regs -> LDS
    {
      float4 va = ax[2 * c], vb = ax[2 * c + 1];
      union { short8 s8; ushort u[8]; } pk;
      pk.u[0] = f2bf(va.x); pk.u[1] = f2bf(va.y);
      pk.u[2] = f2bf(va.z); pk.u[3] = f2bf(va.w);
      pk.u[4] = f2bf(vb.x); pk.u[5] = f2bf(vb.y);
      pk.u[6] = f2bf(vb.z); pk.u[7] = f2bf(vb.w);
      *(short8*)(sA + ar * 64 + ak) = pk.s8;
    }
    __syncthreads();

#pragma unroll
    for (int ks = 0; ks < 64; ks += 32) {
      short8 af = *(const short8*)(sA + (wr * 16 + l16) * 64 + ks + q * 8);
#pragma unroll
      for (int ct = 0; ct < 4; ++ct) {
        int col = wc * 64 + ct * 16 + l16;
        short8 bf = *(const short8*)(sB + col * 64 + ks + q * 8);
        acc[ct] = __builtin_amdgcn_mfma_f32_16x16x32_bf16(af, bf, acc[ct], 0, 0, 0);
      }
    }
    __syncthreads();
  }

  // epilogue 1: store xt (D: row = q*4+reg, col = l16)
#pragma unroll
  for (int ct = 0; ct < 4; ++ct) {
    int col = wc * 64 + ct * 16 + l16;
#pragma unroll
    for (int reg = 0; reg < 4; ++reg) {
      int row = rowBase + wr * 16 + q * 4 + reg;
      xt[((size_t)h * NN + row) * OUT_F + col] = acc[ct][reg];
    }
  }

  // epilogue 2: fused e1/e2
  float pe1[4], pe2[4];
#pragma unroll
  for (int reg = 0; reg < 4; ++reg) { pe1[reg] = 0.f; pe2[reg] = 0.f; }
#pragma unroll
  for (int ct = 0; ct < 4; ++ct) {
    int col = wc * 64 + ct * 16 + l16;
    float a1v = sa[col], a2v = sa[OUT_F + col];
#pragma unroll
    for (int reg = 0; reg < 4; ++reg) {
      pe1[reg] = fmaf(acc[ct][reg], a1v, pe1[reg]);
      pe2[reg] = fmaf(acc[ct][reg], a2v, pe2[reg]);
    }
  }
#pragma unroll
  for (int off = 1; off < 16; off <<= 1) {
#pragma unroll
    for (int reg = 0; reg < 4; ++reg) {
      pe1[reg] += __shfl_xor(pe1[reg], off, 64);
      pe2[reg] += __shfl_xor(pe2[reg], off, 64);
    }
  }
  if (wc == 0 && l16 == 0) {
#pragma unroll
    for (int reg = 0; reg < 4; ++reg) {
      int r = wr * 16 + q * 4 + reg;
      se1[r] = pe1[reg];
      se2[r] = pe2[reg];
    }
  }
  __syncthreads();
  if (wc == 1 && l16 == 0) {
#pragma unroll
    for (int reg = 0; reg < 4; ++reg) {
      int r = wr * 16 + q * 4 + reg;
      se1[r] += pe1[reg];
      se2[r] += pe2[reg];
    }
  }
  __syncthreads();
  if (tid < 32) {
    e1[(size_t)h * NN + rowBase + tid] = se1[tid];
    e2[(size_t)h * NN + rowBase + tid] = se2[tid];
  }
}

// ---------------------------------------------------------------------------
// gat_aggregate (R6-proven): 1 row/block, hoisted scan, parallel reductions,
// x4-unrolled gather. Output raw-reshape layout [h][i][o].
// ---------------------------------------------------------------------------
__global__ __launch_bounds__(256) void gat_aggregate(
    const float* __restrict__ adj, const float* __restrict__ xt,
    const float* __restrict__ e1, const float* __restrict__ e2,
    float* __restrict__ out) {
  __shared__ int s_nbr[NCAP];
  __shared__ float s_sc0[NCAP];
  __shared__ float s_sc1[NCAP];
  __shared__ int s_cnt;
  __shared__ float s_red[4][2];

  const int i = blockIdx.x;
  const int tid = threadIdx.x;
  const int wave = tid >> 6, lane = tid & 63;
  if (tid == 0) s_cnt = 0;
  __syncthreads();

  // phase 1: scan (all 4 wave-wide loads in flight before processing)
  const float4* arow4 = (const float4*)(adj + (size_t)i * NN);
  float4 v[4];
#pragma unroll
  for (int it = 0; it < 4; ++it) v[it] = arow4[tid + it * 256];

#pragma unroll
  for (int it = 0; it < 4; ++it) {
    int j = (tid + it * 256) * 4;
    float vals[4] = {v[it].x, v[it].y, v[it].z, v[it].w};
#pragma unroll
    for (int s = 0; s < 4; ++s) {
      if (vals[s] > 0.f || j + s == i) {
        int p = atomicAdd(&s_cnt, 1);
        if (p < NCAP) s_nbr[p] = j + s;
      }
    }
  }
  __syncthreads();
  const int m = s_cnt < NCAP ? s_cnt : NCAP;

  // phase 2: scores (non-divergent, one gather per thread)
  const float e10 = e1[i];
  const float e11 = e1[NN + i];
  if (tid < m) {
    int j = s_nbr[tid];
    s_sc0[tid] = lrelu(e10 + e2[j]);
    s_sc1[tid] = lrelu(e11 + e2[NN + j]);
  }
  __syncthreads();

  // phase 3: parallel max (both heads)
  float t0 = (tid < m) ? s_sc0[tid] : -3.0e38f;
  float t1 = (tid < m) ? s_sc1[tid] : -3.0e38f;
#pragma unroll
  for (int off = 32; off > 0; off >>= 1) {
    t0 = fmaxf(t0, __shfl_xor(t0, off, 64));
    t1 = fmaxf(t1, __shfl_xor(t1, off, 64));
  }
  if (lane == 0) { s_red[wave][0] = t0; s_red[wave][1] = t1; }
  __syncthreads();
  const float mx0 = fmaxf(fmaxf(s_red[0][0], s_red[1][0]), fmaxf(s_red[2][0], s_red[3][0]));
  const float mx1 = fmaxf(fmaxf(s_red[0][1], s_red[1][1]), fmaxf(s_red[2][1], s_red[3][1]));
  __syncthreads();

  // phase 4: exp + parallel sum
  float g0 = 0.f, g1 = 0.f;
  if (tid < m) {
    g0 = __expf(s_sc0[tid] - mx0); s_sc0[tid] = g0;
    g1 = __expf(s_sc1[tid] - mx1); s_sc1[tid] = g1;
  }
#pragma unroll
  for (int off = 32; off > 0; off >>= 1) {
    g0 += __shfl_xor(g0, off, 64);
    g1 += __shfl_xor(g1, off, 64);
  }
  if (lane == 0) { s_red[wave][0] = g0; s_red[wave][1] = g1; }
  __syncthreads();
  const float l0 = (s_red[0][0] + s_red[1][0]) + (s_red[2][0] + s_red[3][0]);
  const float l1 = (s_red[0][1] + s_red[1][1]) + (s_red[2][1] + s_red[3][1]);

  // phase 5: gather-accumulate (x4 unrolled), post-normalize, ELU
  const int h = tid >> 7;
  const int o = tid & 127;
  const float* pp = h ? s_sc1 : s_sc0;
  const float linv = 1.0f / (h ? l1 : l0);
  const float* xth = xt + (size_t)h * NN * OUT_F + o;

  float acc = 0.f;
  int k = 0;
  for (; k + 4 <= m; k += 4) {
    int j0 = s_nbr[k], j1 = s_nbr[k + 1], j2 = s_nbr[k + 2], j3 = s_nbr[k + 3];
    float q0 = pp[k], q1 = pp[k + 1], q2 = pp[k + 2], q3 = pp[k + 3];
    float w0 = xth[(size_t)j0 * OUT_F], w1 = xth[(size_t)j1 * OUT_F];
    float w2 = xth[(size_t)j2 * OUT_F], w3 = xth[(size_t)j3 * OUT_F];
    acc = fmaf(q0, w0, acc); acc = fmaf(q1, w1, acc);
    acc = fmaf(q2, w2, acc); acc = fmaf(q3, w3, acc);
  }
  for (; k < m; ++k) acc = fmaf(pp[k], xth[(size_t)s_nbr[k] * OUT_F], acc);

  acc *= linv;
  float r = acc > 0.f ? acc : (__expf(acc) - 1.0f);
  out[((size_t)h * NN + i) * OUT_F + o] = r;
}

// ---------------------------------------------------------------------------
extern "C" void kernel_launch(void* const* d_in, const int* in_sizes, int n_in,
                              void* d_out, int out_size, void* d_ws, size_t ws_size,
                              hipStream_t stream) {
  const float* x   = (const float*)d_in[0];
  const float* adj = (const float*)d_in[1];
  const float* W   = (const float*)d_in[2];
  const float* a   = (const float*)d_in[3];
  float* out = (float*)d_out;

  float* xt = (float*)d_ws;                                  // H*N*OUT_F f32 (4 MB)
  float* e1 = xt + (size_t)NHEAD * NN * OUT_F;               // H*N
  float* e2 = e1 + (size_t)NHEAD * NN;                       // H*N
  ushort* Wt = (ushort*)(e2 + (size_t)NHEAD * NN);           // H*OUT_F*IN_F bf16

  prep_w<<<64, 256, 0, stream>>>(W, Wt);
  gemm_mfma<<<dim3(NN / 32, NHEAD), 256, 0, stream>>>(x, Wt, a, xt, e1, e2);
  gat_aggregate<<<NN, 256, 0, stream>>>(adj, xt, e1, e2, out);
}